// Round 15
// baseline (215.960 us; speedup 1.0000x reference)
//
#include <hip/hip_runtime.h>
#include <hip/hip_bf16.h>
#include <math.h>

// Problem constants (fixed by the reference).
#define DEPTHC 2
#define DIMD   256
#define MLPD   1024
#define BB     2
#define NN     2048
#define HH     8
#define HD     32
#define ROWS   (BB * NN)   // 4096 token rows
#define KSPLIT 4
#define TM     32          // rows per tail block

typedef __attribute__((ext_vector_type(8))) short bf16x8;
typedef __attribute__((ext_vector_type(4))) float f32x4;

__device__ __forceinline__ short f2bf(float x) {
    union { float f; unsigned u; } c; c.f = x;
    unsigned u = c.u + (0x7fffu + ((c.u >> 16) & 1u));
    return (short)(u >> 16);
}
__device__ __forceinline__ float bf2f(short s) {
    union { unsigned u; float f; } c; c.u = ((unsigned)(unsigned short)s) << 16;
    return c.f;
}

// ---------------------------------------------------------------------------
// prep: (a) weight transpose+f32->bf16 into MFMA-fragment order (blocks 0..95)
// and (b) LN1 (blocks 96..1119). r13-proven.
// Frag order per (64-n strip, 128-k chunk): unit u = ((ks*4+nt)*4+quad)*16+l16
// holds B[n=nt*16+l16][k=(ks*4+quad)*8 .. +8]. A 32-k slice = 256 contiguous
// units (ks outermost) = 4 KB.
// ---------------------------------------------------------------------------
__global__ __launch_bounds__(256) void prep(
    const float* __restrict__ Wqkv, const float* __restrict__ Wo,
    const float* __restrict__ W1,   const float* __restrict__ W2,
    short* __restrict__ WqkvF, short* __restrict__ WoF,
    short* __restrict__ W1F,   short* __restrict__ W2F,
    const float* __restrict__ x, const float* __restrict__ g,
    const float* __restrict__ be, short* __restrict__ y)
{
    __shared__ short Ts[128][72];

    if (blockIdx.x >= 96) {
        const int wave = threadIdx.x >> 6;
        const int lane = threadIdx.x & 63;
        const int row  = (blockIdx.x - 96) * 4 + wave;
        const int c    = lane * 4;

        const float4 v = *(const float4*)&x[(size_t)row * DIMD + c];
        float s  = v.x + v.y + v.z + v.w;
        float sq = v.x * v.x + v.y * v.y + v.z * v.z + v.w * v.w;
#pragma unroll
        for (int off = 32; off > 0; off >>= 1) {
            s  += __shfl_down(s,  off, 64);
            sq += __shfl_down(sq, off, 64);
        }
        s  = __shfl(s,  0, 64);
        sq = __shfl(sq, 0, 64);

        const float mean = s * (1.f / DIMD);
        const float var  = sq * (1.f / DIMD) - mean * mean;
        const float rstd = rsqrtf(var + 1e-5f);

        const float4 gg = *(const float4*)&g[c];
        const float4 bb = *(const float4*)&be[c];
        short4 ov;
        ov.x = f2bf((v.x - mean) * rstd * gg.x + bb.x);
        ov.y = f2bf((v.y - mean) * rstd * gg.y + bb.y);
        ov.z = f2bf((v.z - mean) * rstd * gg.z + bb.z);
        ov.w = f2bf((v.w - mean) * rstd * gg.w + bb.w);
        *(short4*)&y[(size_t)row * DIMD + c] = ov;
        return;
    }

    int blk = blockIdx.x;
    const float* W; short* WF; int K, N;
    if (blk < 24)      {           W = Wqkv; WF = WqkvF; K = 256;  N = 768;  }
    else if (blk < 32) { blk -= 24; W = Wo;   WF = WoF;   K = 256;  N = 256;  }
    else if (blk < 64) { blk -= 32; W = W1;   WF = W1F;   K = 256;  N = 1024; }
    else               { blk -= 64; W = W2;   WF = W2F;   K = 1024; N = 256;  }
    const int nkc = K >> 7;
    const int bx  = blk / nkc;
    const int kc  = blk % nkc;
    const int n0  = bx * 64;
    const int k0  = kc * 128;

    const int nc  = threadIdx.x & 63;
    const int kr0 = threadIdx.x >> 6;
#pragma unroll
    for (int i = 0; i < 32; ++i) {
        const int kr = kr0 + i * 4;
        Ts[kr][nc] = f2bf(W[(size_t)(k0 + kr) * N + n0 + nc]);
    }
    __syncthreads();

    short* out = WF + ((size_t)bx * nkc + kc) * 8192;
#pragma unroll
    for (int i = 0; i < 4; ++i) {
        const int u    = threadIdx.x + i * 256;
        const int l16  = u & 15;
        const int quad = (u >> 4) & 3;
        const int nt   = (u >> 6) & 3;
        const int ks   = (u >> 8) & 3;
        const int n    = nt * 16 + l16;
        const int kk   = (ks * 4 + quad) * 8;
        bf16x8 v;
#pragma unroll
        for (int j = 0; j < 8; ++j) v[j] = Ts[kk + j][n];
        *(bf16x8*)&out[(size_t)u * 8] = v;
    }
}

// ---------------------------------------------------------------------------
// K-split GEMM for qkv (r12/r13-proven): 4 waves, 64x64 tile, wave covers K/4
// in a private 8 KB LDS region; two-phase merge. VTG scatters V cols into
// vtg[bh][d][token] from the epilogue.
// ---------------------------------------------------------------------------
__global__ __launch_bounds__(256) void gemm_qkv(
    const short* __restrict__ A, const short* __restrict__ WF,
    const float* __restrict__ bias, short* __restrict__ Cv,
    short* __restrict__ vtg)
{
    __shared__ short smem[4][4096];
    constexpr int K = 256, N = 3 * DIMD;

    const int tid  = threadIdx.x;
    const int w    = tid >> 6;
    const int lane = tid & 63;
    const int quad = lane >> 4;
    const int l16  = lane & 15;
    const int n0   = blockIdx.x * 64;
    const int m0   = blockIdx.y * 64;

    const short* wfb  = WF + (size_t)blockIdx.x * 2 * 8192;
    const short* arow = A + (size_t)(m0 + l16) * K + quad * 8;
    short* reg = smem[w];

    f32x4 acc[4][4] = {};

    {
        const int kbase = w * 64;
        const short* src = wfb + ((size_t)(kbase >> 7) * 1024
                                  + (size_t)((kbase >> 6) & 1) * 512) * 8;
#pragma unroll
        for (int i = 0; i < 8; ++i)
            *(bf16x8*)&reg[(i * 64 + lane) * 8] =
                *(const bf16x8*)&src[(size_t)(i * 64 + lane) * 8];
#pragma unroll
        for (int ksl = 0; ksl < 2; ++ksl) {
            const int kk = kbase + ksl * 32;
            bf16x8 af[4];
#pragma unroll
            for (int mt = 0; mt < 4; ++mt)
                af[mt] = *(const bf16x8*)(arow + (size_t)mt * 16 * K + kk);
#pragma unroll
            for (int nt = 0; nt < 4; ++nt) {
                const bf16x8 bf = *(const bf16x8*)
                    &reg[(((ksl * 4 + nt) * 4 + quad) * 16 + l16) * 8];
#pragma unroll
                for (int mt = 0; mt < 4; ++mt)
                    acc[mt][nt] = __builtin_amdgcn_mfma_f32_16x16x32_bf16(
                        af[mt], bf, acc[mt][nt], 0, 0, 0);
            }
        }
    }

#pragma unroll
    for (int p = 0; p < 2; ++p) {
        __syncthreads();
#pragma unroll
        for (int mtl = 0; mtl < 2; ++mtl)
#pragma unroll
            for (int nt = 0; nt < 4; ++nt)
                *(f32x4*)&smem[w][((mtl * 4 + nt) * 64 + lane) * 8] = acc[2 * p + mtl][nt];
        __syncthreads();
        if ((w >> 1) == p) {
            const int mtl = w & 1;
            const int mt  = 2 * p + mtl;
#pragma unroll
            for (int nt = 0; nt < 4; ++nt) {
                const int idx = ((mtl * 4 + nt) * 64 + lane) * 8;
                const f32x4 s0 = *(const f32x4*)&smem[0][idx];
                const f32x4 s1 = *(const f32x4*)&smem[1][idx];
                const f32x4 s2 = *(const f32x4*)&smem[2][idx];
                const f32x4 s3 = *(const f32x4*)&smem[3][idx];
                const f32x4 s  = (s0 + s1) + (s2 + s3);
                const int col  = n0 + nt * 16 + l16;
                const float bb = bias[col];
#pragma unroll
                for (int r = 0; r < 4; ++r) {
                    const int row = m0 + mt * 16 + quad * 4 + r;
                    const short bv = f2bf(s[r] + bb);
                    Cv[(size_t)row * N + col] = bv;
                    if (n0 >= 2 * DIMD) {
                        const int vc = col - 2 * DIMD;
                        const int b  = row >> 11;
                        const int q  = row & (NN - 1);
                        vtg[((size_t)(b * HH + (vc >> 5)) * HD + (vc & 31)) * NN + q] = bv;
                    }
                }
            }
        }
    }
}

// ---------------------------------------------------------------------------
// MFMA flash attention (r8/r14-proven): LDS K/V + exp2 fixed-shift softmax +
// 1-tile register prefetch. 4-way key-split; unnormalized partials out.
// ---------------------------------------------------------------------------
__global__ __launch_bounds__(256) void attn_mfma(
    const short* __restrict__ qkv, const short* __restrict__ vtg,
    short* __restrict__ pO, float* __restrict__ pl)
{
    __shared__ short Ks[64][40];
    __shared__ short Vs[32][72];
    __shared__ short Ps[4][16][72];

    const int tid  = threadIdx.x;
    const int w    = tid >> 6;
    const int lane = tid & 63;
    const int quad = lane >> 4;
    const int l16  = lane & 15;
    const int bh   = blockIdx.y;
    const int b    = bh >> 3;
    const int h    = bh & 7;
    const int ks   = blockIdx.z;
    const int q0   = blockIdx.x * 64 + w * 16;

    const float scale2 = 0.25504606868000365f;   // 32^-0.5 / ln2
    const short* base = qkv + (size_t)b * NN * (3 * DIMD);

    const bf16x8 qfrag =
        *(const bf16x8*)(base + (size_t)(q0 + l16) * (3 * DIMD) + h * HD + quad * 8);

    const int skey = tid >> 2;
    const int sd   = (tid & 3) * 8;
    const int vd   = tid >> 3;
    const int vk   = (tid & 7) * 8;

    const short* kgp = base + (size_t)(ks * (NN / KSPLIT) + skey) * (3 * DIMD)
                       + DIMD + h * HD + sd;
    const short* vgp = vtg + ((size_t)bh * HD + vd) * NN
                       + ks * (NN / KSPLIT) + vk;

    f32x4 oacc0 = {0.f, 0.f, 0.f, 0.f};
    f32x4 oacc1 = {0.f, 0.f, 0.f, 0.f};
    float rowsum[4] = {0.f, 0.f, 0.f, 0.f};

    bf16x8 kreg = *(const bf16x8*)kgp;
    bf16x8 vreg = *(const bf16x8*)vgp;

#pragma unroll 1
    for (int t = 0; t < NN / KSPLIT / 64; ++t) {
        __syncthreads();
        *(bf16x8*)&Ks[skey][sd] = kreg;
        *(bf16x8*)&Vs[vd][vk]   = vreg;
        __syncthreads();

        if (t + 1 < NN / KSPLIT / 64) {
            kreg = *(const bf16x8*)(kgp + (size_t)(t + 1) * 64 * (3 * DIMD));
            vreg = *(const bf16x8*)(vgp + (t + 1) * 64);
        }

        f32x4 s[4];
#pragma unroll
        for (int kt = 0; kt < 4; ++kt) {
            const bf16x8 kf = *(const bf16x8*)&Ks[kt * 16 + l16][quad * 8];
            f32x4 z = {0.f, 0.f, 0.f, 0.f};
            s[kt] = __builtin_amdgcn_mfma_f32_16x16x32_bf16(qfrag, kf, z, 0, 0, 0);
        }

#pragma unroll
        for (int kt = 0; kt < 4; ++kt)
#pragma unroll
            for (int r = 0; r < 4; ++r) {
                const float p = exp2f(fmaf(s[kt][r], scale2, -16.f));
                rowsum[r] += p;
                union { float f; unsigned u; } cv; cv.f = p;
                Ps[w][quad * 4 + r][kt * 16 + l16] = (short)(cv.u >> 16);
            }

#pragma unroll
        for (int c = 0; c < 2; ++c) {
            const bf16x8 pf = *(const bf16x8*)&Ps[w][l16][c * 32 + quad * 8];
            const bf16x8 v0 = *(const bf16x8*)&Vs[l16][c * 32 + quad * 8];
            const bf16x8 v1 = *(const bf16x8*)&Vs[16 + l16][c * 32 + quad * 8];
            oacc0 = __builtin_amdgcn_mfma_f32_16x16x32_bf16(pf, v0, oacc0, 0, 0, 0);
            oacc1 = __builtin_amdgcn_mfma_f32_16x16x32_bf16(pf, v1, oacc1, 0, 0, 0);
        }
    }

#pragma unroll
    for (int off = 1; off <= 8; off <<= 1)
#pragma unroll
        for (int r = 0; r < 4; ++r)
            rowsum[r] += __shfl_xor(rowsum[r], off, 64);

#pragma unroll
    for (int r = 0; r < 4; ++r) {
        const size_t rg = (size_t)bh * NN + q0 + quad * 4 + r;
        pO[(rg * KSPLIT + ks) * HD + l16]      = f2bf(oacc0[r]);
        pO[(rg * KSPLIT + ks) * HD + 16 + l16] = f2bf(oacc1[r]);
        if (l16 == 0) pl[rg * KSPLIT + ks] = rowsum[r];
    }
}

// ---------------------------------------------------------------------------
// tail: the entire post-attention chain, row-local per block of 32 rows.
//   P0 merge(pO,pl) -> zs;  P1 a = zs@Wo + bo + x (a in regs), LN2 -> zs;
//   P2 per round r: wave w computes m1 strip (4r+w) = gelu(z@W1+b1) -> ms[w],
//      then all waves accumulate w2 partials for their own 64-col out strip;
//   P3 out = acc2 + b2 + a.  Only __syncthreads — no grid-wide deps.
// Grid: 128 blocks x 256 threads. LDS ~50.5 KB.
// ---------------------------------------------------------------------------
__global__ __launch_bounds__(256) void tail(
    const short* __restrict__ pO, const float* __restrict__ pl,
    const float* __restrict__ x,
    const short* __restrict__ WoF, const float* __restrict__ bo,
    const float* __restrict__ ln2g, const float* __restrict__ ln2b,
    const short* __restrict__ W1F, const float* __restrict__ b1,
    const short* __restrict__ W2F, const float* __restrict__ b2,
    float* __restrict__ out)
{
    __shared__ short zs[TM][264];        // A0, then z
    __shared__ short ms[4][TM][68];      // m1 tiles (round-shared)
    __shared__ short bs[4][2048];        // per-wave B slice (32-k, 4 KB)
    __shared__ float stats[2][4][TM];    // LN partial sums

    const int tid  = threadIdx.x;
    const int w    = tid >> 6;
    const int lane = tid & 63;
    const int quad = lane >> 4;
    const int l16  = lane & 15;
    const int m0   = blockIdx.x * TM;

    // ---- P0: merged attention output into zs ----
#pragma unroll
    for (int i = 0; i < 4; ++i) {
        const int u   = tid + i * 256;         // 1024 units: row*32 + cc
        const int row = u >> 5;
        const int cc  = u & 31;
        const int h   = cc >> 2;
        const int d0  = (cc & 3) * 8;
        const int grow = m0 + row;
        const int b = grow >> 11, q = grow & (NN - 1);
        const size_t rg = ((size_t)(b * HH + h) * NN + q) * KSPLIT;
        const float L = pl[rg] + pl[rg + 1] + pl[rg + 2] + pl[rg + 3];
        float o[8] = {};
#pragma unroll
        for (int s = 0; s < KSPLIT; ++s) {
            const bf16x8 t = *(const bf16x8*)&pO[(rg + s) * HD + d0];
#pragma unroll
            for (int j = 0; j < 8; ++j) o[j] += bf2f(t[j]);
        }
        const float inv = 1.f / L;
        bf16x8 z8;
#pragma unroll
        for (int j = 0; j < 8; ++j) z8[j] = f2bf(o[j] * inv);
        *(bf16x8*)&zs[row][cc * 8] = z8;
    }
    __syncthreads();

    // ---- P1: wo. wave w -> out cols [w*64, w*64+64), K=256 ----
    f32x4 acc1[2][4] = {};
#pragma unroll
    for (int kk = 0; kk < 256; kk += 32) {
        const short* src = WoF + ((size_t)w * 2 + (kk >> 7)) * 8192
                           + (size_t)((kk >> 5) & 3) * 2048;
#pragma unroll
        for (int i = 0; i < 4; ++i)
            *(bf16x8*)&bs[w][(i * 64 + lane) * 8] =
                *(const bf16x8*)&src[(size_t)(i * 64 + lane) * 8];
        bf16x8 af[2];
#pragma unroll
        for (int mt = 0; mt < 2; ++mt)
            af[mt] = *(const bf16x8*)&zs[l16 + mt * 16][kk + quad * 8];
#pragma unroll
        for (int nt = 0; nt < 4; ++nt) {
            const bf16x8 bf = *(const bf16x8*)&bs[w][((nt * 4 + quad) * 16 + l16) * 8];
#pragma unroll
            for (int mt = 0; mt < 2; ++mt)
                acc1[mt][nt] = __builtin_amdgcn_mfma_f32_16x16x32_bf16(
                    af[mt], bf, acc1[mt][nt], 0, 0, 0);
        }
    }

    // a = acc1 + bo + x; keep in regs; LN2 partial stats
    float a_reg[2][4][4];
    float bov[4], gv[4], bev[4];
#pragma unroll
    for (int nt = 0; nt < 4; ++nt) {
        const int col = w * 64 + nt * 16 + l16;
        bov[nt] = bo[col];
        gv[nt]  = ln2g[col];
        bev[nt] = ln2b[col];
    }
#pragma unroll
    for (int mt = 0; mt < 2; ++mt)
#pragma unroll
    for (int r = 0; r < 4; ++r) {
        const int grow = m0 + mt * 16 + quad * 4 + r;
        float s = 0.f, sq = 0.f;
#pragma unroll
        for (int nt = 0; nt < 4; ++nt) {
            const float v = acc1[mt][nt][r] + bov[nt]
                          + x[(size_t)grow * DIMD + w * 64 + nt * 16 + l16];
            a_reg[mt][r][nt] = v;
            s += v; sq += v * v;
        }
#pragma unroll
        for (int off = 1; off <= 8; off <<= 1) {
            s  += __shfl_xor(s,  off, 64);
            sq += __shfl_xor(sq, off, 64);
        }
        if (l16 == 0) {
            stats[0][w][mt * 16 + quad * 4 + r] = s;
            stats[1][w][mt * 16 + quad * 4 + r] = sq;
        }
    }
    __syncthreads();   // stats ready; zs reads (P1) complete — safe to overwrite

    // normalize and write z into zs
#pragma unroll
    for (int mt = 0; mt < 2; ++mt)
#pragma unroll
    for (int r = 0; r < 4; ++r) {
        const int lrow = mt * 16 + quad * 4 + r;
        const float s  = stats[0][0][lrow] + stats[0][1][lrow]
                       + stats[0][2][lrow] + stats[0][3][lrow];
        const float sq = stats[1][0][lrow] + stats[1][1][lrow]
                       + stats[1][2][lrow] + stats[1][3][lrow];
        const float mean = s * (1.f / DIMD);
        const float var  = sq * (1.f / DIMD) - mean * mean;
        const float rstd = rsqrtf(var + 1e-5f);
#pragma unroll
        for (int nt = 0; nt < 4; ++nt)
            zs[lrow][w * 64 + nt * 16 + l16] =
                f2bf((a_reg[mt][r][nt] - mean) * rstd * gv[nt] + bev[nt]);
    }
    __syncthreads();   // z complete

    // ---- P2: rounds of (m1 strip -> shared) + w2 partial accumulate ----
    f32x4 acc2[2][4] = {};
#pragma unroll 1
    for (int rd = 0; rd < 4; ++rd) {
        const int st = rd * 4 + w;           // this wave's w1 strip
        f32x4 accm[2][4] = {};
#pragma unroll
        for (int kk = 0; kk < 256; kk += 32) {
            const short* src = W1F + ((size_t)st * 2 + (kk >> 7)) * 8192
                               + (size_t)((kk >> 5) & 3) * 2048;
#pragma unroll
            for (int i = 0; i < 4; ++i)
                *(bf16x8*)&bs[w][(i * 64 + lane) * 8] =
                    *(const bf16x8*)&src[(size_t)(i * 64 + lane) * 8];
            bf16x8 af[2];
#pragma unroll
            for (int mt = 0; mt < 2; ++mt)
                af[mt] = *(const bf16x8*)&zs[l16 + mt * 16][kk + quad * 8];
#pragma unroll
            for (int nt = 0; nt < 4; ++nt) {
                const bf16x8 bf = *(const bf16x8*)&bs[w][((nt * 4 + quad) * 16 + l16) * 8];
#pragma unroll
                for (int mt = 0; mt < 2; ++mt)
                    accm[mt][nt] = __builtin_amdgcn_mfma_f32_16x16x32_bf16(
                        af[mt], bf, accm[mt][nt], 0, 0, 0);
            }
        }
        // gelu + publish m1 tile
#pragma unroll
        for (int mt = 0; mt < 2; ++mt)
#pragma unroll
        for (int nt = 0; nt < 4; ++nt)
#pragma unroll
        for (int r = 0; r < 4; ++r) {
            float v = accm[mt][nt][r] + b1[st * 64 + nt * 16 + l16];
            v = 0.5f * v * (1.f + erff(v * 0.70710678118f));
            ms[w][mt * 16 + quad * 4 + r][nt * 16 + l16] = f2bf(v);
        }
        __syncthreads();   // all 4 tiles of round rd visible

        // w2 partial: k rows (rd*4+j)*64, out strip w
#pragma unroll
        for (int j = 0; j < 4; ++j)
#pragma unroll
        for (int ksl = 0; ksl < 2; ++ksl) {
            const int kglob = (rd * 4 + j) * 64 + ksl * 32;
            const short* src = W2F + ((size_t)w * 8 + (kglob >> 7)) * 8192
                               + (size_t)((kglob >> 5) & 3) * 2048;
#pragma unroll
            for (int i = 0; i < 4; ++i)
                *(bf16x8*)&bs[w][(i * 64 + lane) * 8] =
                    *(const bf16x8*)&src[(size_t)(i * 64 + lane) * 8];
            bf16x8 af[2];
#pragma unroll
            for (int mt = 0; mt < 2; ++mt)
                af[mt] = *(const bf16x8*)&ms[j][l16 + mt * 16][ksl * 32 + quad * 8];
#pragma unroll
            for (int nt = 0; nt < 4; ++nt) {
                const bf16x8 bf = *(const bf16x8*)&bs[w][((nt * 4 + quad) * 16 + l16) * 8];
#pragma unroll
                for (int mt = 0; mt < 2; ++mt)
                    acc2[mt][nt] = __builtin_amdgcn_mfma_f32_16x16x32_bf16(
                        af[mt], bf, acc2[mt][nt], 0, 0, 0);
            }
        }
        __syncthreads();   // before ms overwritten next round
    }

    // ---- P3: out = acc2 + b2 + a ----
#pragma unroll
    for (int mt = 0; mt < 2; ++mt)
#pragma unroll
    for (int nt = 0; nt < 4; ++nt) {
        const int col = w * 64 + nt * 16 + l16;
        const float bb = b2[col];
#pragma unroll
        for (int r = 0; r < 4; ++r) {
            const int grow = m0 + mt * 16 + quad * 4 + r;
            out[(size_t)grow * DIMD + col] = acc2[mt][nt][r] + bb + a_reg[mt][r][nt];
        }
    }
}

// ---------------------------------------------------------------------------
// Launch: only the LAST layer matters (reference never feeds `out` back).
// 4 dispatches.
// ---------------------------------------------------------------------------
extern "C" void kernel_launch(void* const* d_in, const int* in_sizes, int n_in,
                              void* d_out, int out_size, void* d_ws, size_t ws_size,
                              hipStream_t stream)
{
    const int L = DEPTHC - 1;
    const float* x     = (const float*)d_in[0];
    const float* ln1_g = (const float*)d_in[1]  + L * DIMD;
    const float* ln1_b = (const float*)d_in[2]  + L * DIMD;
    const float* Wqkv  = (const float*)d_in[3]  + (size_t)L * DIMD * 3 * DIMD;
    const float* bqkv  = (const float*)d_in[4]  + L * 3 * DIMD;
    const float* Wo    = (const float*)d_in[5]  + (size_t)L * DIMD * DIMD;
    const float* bo    = (const float*)d_in[6]  + L * DIMD;
    const float* ln2_g = (const float*)d_in[7]  + L * DIMD;
    const float* ln2_b = (const float*)d_in[8]  + L * DIMD;
    const float* W1    = (const float*)d_in[9]  + (size_t)L * DIMD * MLPD;
    const float* b1    = (const float*)d_in[10] + L * MLPD;
    const float* W2    = (const float*)d_in[11] + (size_t)L * MLPD * DIMD;
    const float* b2    = (const float*)d_in[12] + L * DIMD;
    float* out = (float*)d_out;

    // Workspace layout (shorts unless noted):
    short* WqkvF = (short*)d_ws;                          // 12*2*8192
    short* WoF   = WqkvF + 12 * 2 * 8192;                 // 4*2*8192
    short* W1F   = WoF   + 4 * 2 * 8192;                  // 16*2*8192
    short* W2F   = W1F   + 16 * 2 * 8192;                 // 4*8*8192
    short* ybf   = W2F   + 4 * 8 * 8192;                  // [4096][256]
    short* qkvbf = ybf   + (size_t)ROWS * DIMD;           // [4096][768]
    short* vtg   = qkvbf + (size_t)ROWS * 3 * DIMD;       // [16][32][2048]
    short* pO    = vtg   + (size_t)16 * HD * NN;          // [32768][4][32]
    float* pl    = (float*)(pO + (size_t)16 * NN * KSPLIT * HD); // [32768][4]

    // 1) weights -> frag order  AND  y = LN1(x)
    prep<<<96 + ROWS / 4, 256, 0, stream>>>(
        Wqkv, Wo, W1, W2, WqkvF, WoF, W1F, W2F, x, ln1_g, ln1_b, ybf);

    // 2) qkv = y @ Wqkv + bqkv  (bf16 out) + fused V-transpose
    gemm_qkv<<<dim3(12, 64), 256, 0, stream>>>(ybf, WqkvF, bqkv, qkvbf, vtg);

    // 3) attention partials (4-way key split)
    attn_mfma<<<dim3(NN / 64, BB * HH, KSPLIT), 256, 0, stream>>>(qkvbf, vtg, pO, pl);

    // 4) merge + wo + LN2 + W1/gelu + W2 (+residuals), row-local
    tail<<<ROWS / TM, 256, 0, stream>>>(
        pO, pl, x, WoF, bo, ln2_g, ln2_b, W1F, b1, W2F, b2, out);
}

// Round 16
// 167.983 us; speedup vs baseline: 1.2856x; 1.2856x over previous
//
#include <hip/hip_runtime.h>
#include <hip/hip_bf16.h>
#include <math.h>

// Problem constants (fixed by the reference).
#define DEPTHC 2
#define DIMD   256
#define MLPD   1024
#define BB     2
#define NN     2048
#define HH     8
#define HD     32
#define ROWS   (BB * NN)   // 4096 token rows
#define KSPLIT 4

typedef __attribute__((ext_vector_type(8))) short bf16x8;
typedef __attribute__((ext_vector_type(4))) float f32x4;

__device__ __forceinline__ short f2bf(float x) {
    union { float f; unsigned u; } c; c.f = x;
    unsigned u = c.u + (0x7fffu + ((c.u >> 16) & 1u));
    return (short)(u >> 16);
}
__device__ __forceinline__ float bf2f(short s) {
    union { unsigned u; float f; } c; c.u = ((unsigned)(unsigned short)s) << 16;
    return c.f;
}

// ---------------------------------------------------------------------------
// prep: (a) weight transpose+f32->bf16 into MFMA-fragment order (blocks 0..95)
// and (b) LN1 (blocks 96..1119). Independent read-only work, one launch.
// ---------------------------------------------------------------------------
__global__ __launch_bounds__(256) void prep(
    const float* __restrict__ Wqkv, const float* __restrict__ Wo,
    const float* __restrict__ W1,   const float* __restrict__ W2,
    short* __restrict__ WqkvF, short* __restrict__ WoF,
    short* __restrict__ W1F,   short* __restrict__ W2F,
    const float* __restrict__ x, const float* __restrict__ g,
    const float* __restrict__ be, short* __restrict__ y)
{
    __shared__ short Ts[128][72];

    if (blockIdx.x >= 96) {
        const int wave = threadIdx.x >> 6;
        const int lane = threadIdx.x & 63;
        const int row  = (blockIdx.x - 96) * 4 + wave;
        const int c    = lane * 4;

        const float4 v = *(const float4*)&x[(size_t)row * DIMD + c];
        float s  = v.x + v.y + v.z + v.w;
        float sq = v.x * v.x + v.y * v.y + v.z * v.z + v.w * v.w;
#pragma unroll
        for (int off = 32; off > 0; off >>= 1) {
            s  += __shfl_down(s,  off, 64);
            sq += __shfl_down(sq, off, 64);
        }
        s  = __shfl(s,  0, 64);
        sq = __shfl(sq, 0, 64);

        const float mean = s * (1.f / DIMD);
        const float var  = sq * (1.f / DIMD) - mean * mean;
        const float rstd = rsqrtf(var + 1e-5f);

        const float4 gg = *(const float4*)&g[c];
        const float4 bb = *(const float4*)&be[c];
        short4 ov;
        ov.x = f2bf((v.x - mean) * rstd * gg.x + bb.x);
        ov.y = f2bf((v.y - mean) * rstd * gg.y + bb.y);
        ov.z = f2bf((v.z - mean) * rstd * gg.z + bb.z);
        ov.w = f2bf((v.w - mean) * rstd * gg.w + bb.w);
        *(short4*)&y[(size_t)row * DIMD + c] = ov;
        return;
    }

    int blk = blockIdx.x;
    const float* W; short* WF; int K, N;
    if (blk < 24)      {           W = Wqkv; WF = WqkvF; K = 256;  N = 768;  }
    else if (blk < 32) { blk -= 24; W = Wo;   WF = WoF;   K = 256;  N = 256;  }
    else if (blk < 64) { blk -= 32; W = W1;   WF = W1F;   K = 256;  N = 1024; }
    else               { blk -= 64; W = W2;   WF = W2F;   K = 1024; N = 256;  }
    const int nkc = K >> 7;
    const int bx  = blk / nkc;
    const int kc  = blk % nkc;
    const int n0  = bx * 64;
    const int k0  = kc * 128;

    const int nc  = threadIdx.x & 63;
    const int kr0 = threadIdx.x >> 6;
#pragma unroll
    for (int i = 0; i < 32; ++i) {
        const int kr = kr0 + i * 4;
        Ts[kr][nc] = f2bf(W[(size_t)(k0 + kr) * N + n0 + nc]);
    }
    __syncthreads();

    short* out = WF + ((size_t)bx * nkc + kc) * 8192;
#pragma unroll
    for (int i = 0; i < 4; ++i) {
        const int u    = threadIdx.x + i * 256;
        const int l16  = u & 15;
        const int quad = (u >> 4) & 3;
        const int nt   = (u >> 6) & 3;
        const int ks   = (u >> 8) & 3;
        const int n    = nt * 16 + l16;
        const int kk   = (ks * 4 + quad) * 8;
        bf16x8 v;
#pragma unroll
        for (int j = 0; j < 8; ++j) v[j] = Ts[kk + j][n];
        *(bf16x8*)&out[(size_t)u * 8] = v;
    }
}

// ---------------------------------------------------------------------------
// K-split GEMM (r12-proven core): 4 waves, 64x64 tile, wave covers K/4 with
// a private 8 KB LDS region (no barriers during compute); two-phase merge.
// VTG: additionally scatter V-range columns (col>=512) into vtg[bh][d][token].
// ---------------------------------------------------------------------------
template <int K, bool GELU, bool RES, bool OBF, bool VTG>
__global__ __launch_bounds__(256) void gemm_ks(
    const short* __restrict__ A, const short* __restrict__ WF,
    const float* __restrict__ bias, const float* __restrict__ R,
    void* __restrict__ Cv, int N, short* __restrict__ vtg)
{
    __shared__ short smem[4][4096];

    const int tid  = threadIdx.x;
    const int w    = tid >> 6;
    const int lane = tid & 63;
    const int quad = lane >> 4;
    const int l16  = lane & 15;
    const int n0   = blockIdx.x * 64;
    const int m0   = blockIdx.y * 64;
    constexpr int NKC   = K / 128;
    constexpr int SLICE = K / 4;
    constexpr int NHC   = SLICE / 64;

    const short* wfb  = WF + (size_t)blockIdx.x * NKC * 8192;
    const short* arow = A + (size_t)(m0 + l16) * K + quad * 8;
    short* reg = smem[w];

    f32x4 acc[4][4] = {};

#pragma unroll
    for (int hc = 0; hc < NHC; ++hc) {
        const int kbase = w * SLICE + hc * 64;
        const short* src = wfb +
            ((size_t)(kbase >> 7) * 1024 + (size_t)((kbase >> 6) & 1) * 512) * 8;
#pragma unroll
        for (int i = 0; i < 8; ++i)
            *(bf16x8*)&reg[(i * 64 + lane) * 8] =
                *(const bf16x8*)&src[(size_t)(i * 64 + lane) * 8];

#pragma unroll
        for (int ksl = 0; ksl < 2; ++ksl) {
            const int kk = kbase + ksl * 32;
            bf16x8 af[4];
#pragma unroll
            for (int mt = 0; mt < 4; ++mt)
                af[mt] = *(const bf16x8*)(arow + (size_t)mt * 16 * K + kk);
#pragma unroll
            for (int nt = 0; nt < 4; ++nt) {
                const bf16x8 bf = *(const bf16x8*)
                    &reg[(((ksl * 4 + nt) * 4 + quad) * 16 + l16) * 8];
#pragma unroll
                for (int mt = 0; mt < 4; ++mt)
                    acc[mt][nt] = __builtin_amdgcn_mfma_f32_16x16x32_bf16(
                        af[mt], bf, acc[mt][nt], 0, 0, 0);
            }
        }
    }

    // ---- two-phase K-split merge + epilogue ----
#pragma unroll
    for (int p = 0; p < 2; ++p) {
        __syncthreads();
#pragma unroll
        for (int mtl = 0; mtl < 2; ++mtl)
#pragma unroll
            for (int nt = 0; nt < 4; ++nt)
                *(f32x4*)&smem[w][((mtl * 4 + nt) * 64 + lane) * 8] = acc[2 * p + mtl][nt];
        __syncthreads();
        if ((w >> 1) == p) {
            const int mtl = w & 1;
            const int mt  = 2 * p + mtl;
#pragma unroll
            for (int nt = 0; nt < 4; ++nt) {
                const int idx = ((mtl * 4 + nt) * 64 + lane) * 8;
                const f32x4 s0 = *(const f32x4*)&smem[0][idx];
                const f32x4 s1 = *(const f32x4*)&smem[1][idx];
                const f32x4 s2 = *(const f32x4*)&smem[2][idx];
                const f32x4 s3 = *(const f32x4*)&smem[3][idx];
                const f32x4 s  = (s0 + s1) + (s2 + s3);
                const int col  = n0 + nt * 16 + l16;
                const float bb = bias[col];
#pragma unroll
                for (int r = 0; r < 4; ++r) {
                    const int row = m0 + mt * 16 + quad * 4 + r;
                    float v = s[r] + bb;
                    if (RES)  v += R[(size_t)row * N + col];
                    if (GELU) v = 0.5f * v * (1.f + erff(v * 0.70710678118f));
                    const short bv = f2bf(v);
                    if (OBF) ((short*)Cv)[(size_t)row * N + col] = bv;
                    else     ((float*)Cv)[(size_t)row * N + col] = v;
                    if (VTG && n0 >= 2 * DIMD) {
                        const int vc = col - 2 * DIMD;     // 0..255
                        const int b  = row >> 11;
                        const int q  = row & (NN - 1);
                        const int h  = vc >> 5;
                        const int d  = vc & 31;
                        vtg[((size_t)(b * HH + h) * HD + d) * NN + q] = bv;
                    }
                }
            }
        }
    }
}

// ---------------------------------------------------------------------------
// LayerNorm (for LN2): one wave per row, 4 rows/block. f32 in, bf16 out.
// ---------------------------------------------------------------------------
__global__ __launch_bounds__(256) void ln_kernel(
    const float* __restrict__ x, const float* __restrict__ g,
    const float* __restrict__ bta, short* __restrict__ y)
{
    const int wave = threadIdx.x >> 6;
    const int lane = threadIdx.x & 63;
    const int row  = blockIdx.x * 4 + wave;
    const int c    = lane * 4;

    const float4 v = *(const float4*)&x[(size_t)row * DIMD + c];
    float s  = v.x + v.y + v.z + v.w;
    float sq = v.x * v.x + v.y * v.y + v.z * v.z + v.w * v.w;
#pragma unroll
    for (int off = 32; off > 0; off >>= 1) {
        s  += __shfl_down(s,  off, 64);
        sq += __shfl_down(sq, off, 64);
    }
    s  = __shfl(s,  0, 64);
    sq = __shfl(sq, 0, 64);

    const float mean = s * (1.f / DIMD);
    const float var  = sq * (1.f / DIMD) - mean * mean;
    const float rstd = rsqrtf(var + 1e-5f);

    const float4 gg = *(const float4*)&g[c];
    const float4 bb = *(const float4*)&bta[c];
    short4 ov;
    ov.x = f2bf((v.x - mean) * rstd * gg.x + bb.x);
    ov.y = f2bf((v.y - mean) * rstd * gg.y + bb.y);
    ov.z = f2bf((v.z - mean) * rstd * gg.z + bb.z);
    ov.w = f2bf((v.w - mean) * rstd * gg.w + bb.w);
    *(short4*)&y[(size_t)row * DIMD + c] = ov;
}

// ---------------------------------------------------------------------------
// MFMA flash attention (round-8/12 proven) with exp2-form fixed-shift softmax:
// p = exp2(s*(scale/ln2) - 16) == exp(s*scale - 16ln2); shift cancels in O/L.
// ---------------------------------------------------------------------------
__global__ __launch_bounds__(256) void attn_mfma(
    const short* __restrict__ qkv, const short* __restrict__ vtg,
    short* __restrict__ pO, float* __restrict__ pl)
{
    __shared__ short Ks[64][40];
    __shared__ short Vs[32][72];
    __shared__ short Ps[4][16][72];

    const int tid  = threadIdx.x;
    const int w    = tid >> 6;
    const int lane = tid & 63;
    const int quad = lane >> 4;
    const int l16  = lane & 15;
    const int bh   = blockIdx.y;
    const int b    = bh >> 3;
    const int h    = bh & 7;
    const int ks   = blockIdx.z;
    const int q0   = blockIdx.x * 64 + w * 16;

    const float scale2 = 0.25504606868000365f;   // 32^-0.5 / ln2
    const short* base = qkv + (size_t)b * NN * (3 * DIMD);

    const bf16x8 qfrag =
        *(const bf16x8*)(base + (size_t)(q0 + l16) * (3 * DIMD) + h * HD + quad * 8);

    const int skey = tid >> 2;
    const int sd   = (tid & 3) * 8;
    const int vd   = tid >> 3;
    const int vk   = (tid & 7) * 8;

    const short* kgp = base + (size_t)(ks * (NN / KSPLIT) + skey) * (3 * DIMD)
                       + DIMD + h * HD + sd;
    const short* vgp = vtg + ((size_t)bh * HD + vd) * NN
                       + ks * (NN / KSPLIT) + vk;

    f32x4 oacc0 = {0.f, 0.f, 0.f, 0.f};
    f32x4 oacc1 = {0.f, 0.f, 0.f, 0.f};
    float rowsum[4] = {0.f, 0.f, 0.f, 0.f};

    bf16x8 kreg = *(const bf16x8*)kgp;
    bf16x8 vreg = *(const bf16x8*)vgp;

#pragma unroll 1
    for (int t = 0; t < NN / KSPLIT / 64; ++t) {
        __syncthreads();
        *(bf16x8*)&Ks[skey][sd] = kreg;
        *(bf16x8*)&Vs[vd][vk]   = vreg;
        __syncthreads();

        if (t + 1 < NN / KSPLIT / 64) {
            kreg = *(const bf16x8*)(kgp + (size_t)(t + 1) * 64 * (3 * DIMD));
            vreg = *(const bf16x8*)(vgp + (t + 1) * 64);
        }

        f32x4 s[4];
#pragma unroll
        for (int kt = 0; kt < 4; ++kt) {
            const bf16x8 kf = *(const bf16x8*)&Ks[kt * 16 + l16][quad * 8];
            f32x4 z = {0.f, 0.f, 0.f, 0.f};
            s[kt] = __builtin_amdgcn_mfma_f32_16x16x32_bf16(qfrag, kf, z, 0, 0, 0);
        }

#pragma unroll
        for (int kt = 0; kt < 4; ++kt)
#pragma unroll
            for (int r = 0; r < 4; ++r) {
                const float p = exp2f(fmaf(s[kt][r], scale2, -16.f));
                rowsum[r] += p;
                union { float f; unsigned u; } cv; cv.f = p;
                Ps[w][quad * 4 + r][kt * 16 + l16] = (short)(cv.u >> 16);
            }

#pragma unroll
        for (int c = 0; c < 2; ++c) {
            const bf16x8 pf = *(const bf16x8*)&Ps[w][l16][c * 32 + quad * 8];
            const bf16x8 v0 = *(const bf16x8*)&Vs[l16][c * 32 + quad * 8];
            const bf16x8 v1 = *(const bf16x8*)&Vs[16 + l16][c * 32 + quad * 8];
            oacc0 = __builtin_amdgcn_mfma_f32_16x16x32_bf16(pf, v0, oacc0, 0, 0, 0);
            oacc1 = __builtin_amdgcn_mfma_f32_16x16x32_bf16(pf, v1, oacc1, 0, 0, 0);
        }
    }

#pragma unroll
    for (int off = 1; off <= 8; off <<= 1)
#pragma unroll
        for (int r = 0; r < 4; ++r)
            rowsum[r] += __shfl_xor(rowsum[r], off, 64);

#pragma unroll
    for (int r = 0; r < 4; ++r) {
        const size_t rg = (size_t)bh * NN + q0 + quad * 4 + r;
        pO[(rg * KSPLIT + ks) * HD + l16]      = f2bf(oacc0[r]);
        pO[(rg * KSPLIT + ks) * HD + 16 + l16] = f2bf(oacc1[r]);
        if (l16 == 0) pl[rg * KSPLIT + ks] = rowsum[r];
    }
}

// ---------------------------------------------------------------------------
// Merge KSPLIT partials (shared fixed shift -> plain sum), bf16 out.
// ---------------------------------------------------------------------------
__global__ __launch_bounds__(256) void attn_merge(
    const short* __restrict__ pO, const float* __restrict__ pl,
    short* __restrict__ o)
{
    const int idx = blockIdx.x * 256 + threadIdx.x;
    const int r   = idx >> 5;
    const int d   = idx & 31;

    float L = 0.f, O = 0.f;
#pragma unroll
    for (int s = 0; s < KSPLIT; ++s) {
        L += pl[r * KSPLIT + s];
        O += bf2f(pO[(size_t)(r * KSPLIT + s) * HD + d]);
    }
    const int bh = r >> 11;
    const int q  = r & (NN - 1);
    const int b  = bh >> 3;
    const int h  = bh & 7;
    o[((size_t)(b * NN + q)) * DIMD + h * HD + d] = f2bf(O / L);
}

// ---------------------------------------------------------------------------
// Launch: only the LAST layer matters (reference never feeds `out` back).
// 8 dispatches — the best-measured configuration (166.5 µs, round 13).
// ---------------------------------------------------------------------------
extern "C" void kernel_launch(void* const* d_in, const int* in_sizes, int n_in,
                              void* d_out, int out_size, void* d_ws, size_t ws_size,
                              hipStream_t stream)
{
    const int L = DEPTHC - 1;
    const float* x     = (const float*)d_in[0];
    const float* ln1_g = (const float*)d_in[1]  + L * DIMD;
    const float* ln1_b = (const float*)d_in[2]  + L * DIMD;
    const float* Wqkv  = (const float*)d_in[3]  + (size_t)L * DIMD * 3 * DIMD;
    const float* bqkv  = (const float*)d_in[4]  + L * 3 * DIMD;
    const float* Wo    = (const float*)d_in[5]  + (size_t)L * DIMD * DIMD;
    const float* bo    = (const float*)d_in[6]  + L * DIMD;
    const float* ln2_g = (const float*)d_in[7]  + L * DIMD;
    const float* ln2_b = (const float*)d_in[8]  + L * DIMD;
    const float* W1    = (const float*)d_in[9]  + (size_t)L * DIMD * MLPD;
    const float* b1    = (const float*)d_in[10] + L * MLPD;
    const float* W2    = (const float*)d_in[11] + (size_t)L * MLPD * DIMD;
    const float* b2    = (const float*)d_in[12] + L * DIMD;
    float* out = (float*)d_out;

    // Workspace layout (shorts unless noted):
    short* WqkvF = (short*)d_ws;                          // 12*2*8192
    short* WoF   = WqkvF + 12 * 2 * 8192;                 // 4*2*8192
    short* W1F   = WoF   + 4 * 2 * 8192;                  // 16*2*8192
    short* W2F   = W1F   + 16 * 2 * 8192;                 // 4*8*8192
    short* ybf   = W2F   + 4 * 8 * 8192;                  // [4096][256]
    short* zbf   = ybf   + (size_t)ROWS * DIMD;           // [4096][256]
    short* qkvbf = zbf   + (size_t)ROWS * DIMD;           // [4096][768]
    short* vtg   = qkvbf + (size_t)ROWS * 3 * DIMD;       // [16][32][2048]
    short* obf   = vtg   + (size_t)16 * HD * NN;          // [4096][256]
    short* pO    = obf   + (size_t)ROWS * DIMD;           // [32768][4][32]
    short* m1bf  = pO    + (size_t)16 * NN * KSPLIT * HD; // [4096][1024]
    float* pl    = (float*)(m1bf + (size_t)ROWS * MLPD);  // [32768][4]
    float* a     = pl + (size_t)16 * NN * KSPLIT;         // [4096][256] f32

    // 1) weights -> frag order  AND  y = LN1(x), one launch
    prep<<<96 + ROWS / 4, 256, 0, stream>>>(
        Wqkv, Wo, W1, W2, WqkvF, WoF, W1F, W2F, x, ln1_g, ln1_b, ybf);

    // 2) qkv = y @ Wqkv + bqkv  (bf16 out) + fused V-transpose into vtg
    gemm_ks<256, false, false, true, true><<<dim3(12, 64), 256, 0, stream>>>(
        ybf, WqkvF, bqkv, nullptr, qkvbf, 3 * DIMD, vtg);

    // 3) attention partials (4-way key split)
    attn_mfma<<<dim3(NN / 64, BB * HH, KSPLIT), 256, 0, stream>>>(qkvbf, vtg, pO, pl);

    // 4) merge partials -> obf
    attn_merge<<<(16 * NN * HD) / 256, 256, 0, stream>>>(pO, pl, obf);

    // 5) a = o @ Wo + bo + x  (f32 out)
    gemm_ks<256, false, true, false, false><<<dim3(4, 64), 256, 0, stream>>>(
        obf, WoF, bo, x, a, DIMD, nullptr);

    // 6) z = LN2(a)
    ln_kernel<<<ROWS / 4, 256, 0, stream>>>(a, ln2_g, ln2_b, zbf);

    // 7) m1 = gelu(z @ W1 + b1)  (bf16 out)
    gemm_ks<256, true, false, true, false><<<dim3(16, 64), 256, 0, stream>>>(
        zbf, W1F, b1, nullptr, m1bf, MLPD, nullptr);

    // 8) out = m1 @ W2 + b2 + a  (f32 out)
    gemm_ks<1024, false, true, false, false><<<dim3(4, 64), 256, 0, stream>>>(
        m1bf, W2F, b2, a, out, DIMD, nullptr);
}